// Round 6
// baseline (182.835 us; speedup 1.0000x reference)
//
#include <hip/hip_runtime.h>
#include <math.h>
#include <stdint.h>

// Problem constants
#define TM 16384   // B*C*T rows
#define NN 512     // DOUT
#define KDIM 1536  // DIN
#define BM 128
#define BN 128
#define BKS 32
#define NKT 48     // total K-steps (full K per block: tanh needs complete z)

typedef _Float16 f16x8 __attribute__((ext_vector_type(8)));
typedef float f32x4 __attribute__((ext_vector_type(4)));
typedef float f32x16 __attribute__((ext_vector_type(16)));

__device__ __forceinline__ unsigned short f16bits(_Float16 h) {
  union { _Float16 h; unsigned short u; } cv; cv.h = h; return cv.u;
}

// B-tile swizzle (fp16, 64B rows, 4x16B chunks): chunk' = chunk ^ ((row>>1)&3).
__device__ __forceinline__ int swz_chunk(int row, int chunk) {
  return chunk ^ ((row >> 1) & 3);
}

__device__ __forceinline__ void gload_lds16(const void* g, void* l) {
  __builtin_amdgcn_global_load_lds(
      (const __attribute__((address_space(1))) unsigned int*)g,
      (__attribute__((address_space(3))) unsigned int*)l, 16, 0, 0);
}

// ---------------------------------------------------------------------------
// Kernel 1: W1 [K=1536][N=512] fp32 -> pre-swizzled tiled fp16 hi/lo images.
// ws layout: [nblk 4][kt 48][hl 2][8192B tile]; tile image byte:
//   row*64 + swz_chunk(row, k>>3)*16 + (k&7)*2   (row = n within block)
// ---------------------------------------------------------------------------
__global__ __launch_bounds__(256) void convert_w1_kernel(
    const float* __restrict__ W1,
    unsigned short* __restrict__ W1ws)
{
  const int kt = blockIdx.x;       // 0..47
  const int nb = blockIdx.y;       // 0..3
  const int tid = threadIdx.x;
  const int k0 = kt * BKS, n0 = nb * BN;
  const size_t tbase = ((size_t)(nb * NKT + kt) * 2) * 4096;  // u16 units
#pragma unroll
  for (int i = 0; i < 16; ++i) {
    int idx = tid + i * 256;       // 0..4095
    int nn = idx & 127, kk = idx >> 7;
    float f = W1[(size_t)(k0 + kk) * NN + n0 + nn];
    _Float16 h = (_Float16)f;
    _Float16 l = (_Float16)((f - (float)h) * 2048.0f);
    int off16 = nn * 32 + (swz_chunk(nn, kk >> 3) << 3) + (kk & 7);
    W1ws[tbase + off16] = f16bits(h);
    W1ws[tbase + 4096 + off16] = f16bits(l);
  }
}

// ---------------------------------------------------------------------------
// Kernel 2: GEMM z = q @ W1 + b, fp16 split-3 via mfma_f32_32x32x16_f16,
// fused tanh*Vw epilogue. 8 waves (512 thr), wave-tile 32x64 (1 m-frag x
// 2 n-frags of 32). Dbuf LDS + gload_lds + counted vmcnt(4).
// A staged raw fp32 source-swizzled; hi/lo split in registers.
// ---------------------------------------------------------------------------
__global__ __launch_bounds__(512, 4) void gemm_score_kernel(
    const float* __restrict__ query,
    const unsigned short* __restrict__ W1ws,
    const float* __restrict__ W1b,
    const float* __restrict__ Vw,
    float* __restrict__ raw_part)
{
  __shared__ __align__(16) char ldsb[2][32768];
  __shared__ float red[2][BM];

  const int tid = threadIdx.x;
  const int lane = tid & 63;
  const int w = tid >> 6;                  // 0..7
  const int wr = w & 3, wc = w >> 2;       // 4 m-groups(32) x 2 n-groups(64)
  const int l31 = lane & 31;
  const int lk = lane >> 5;                // k-half 0/1 (8 elems each)

  // XCD-chunked bijective swizzle (512 = 8 XCD * 64), n innermost per XCD
  const int bid = blockIdx.x;
  const int lin = (bid & 7) * 64 + (bid >> 3);
  const int mb = lin >> 2, nb = lin & 3;
  const int m0 = mb * BM, n0 = nb * BN;

  f32x16 acc[2], acc2[2];   // per n-frag: hh and (hl+lh)*2^11
#pragma unroll
  for (int n = 0; n < 2; ++n) {
#pragma unroll
    for (int e = 0; e < 16; ++e) { acc[n][e] = 0.f; acc2[n][e] = 0.f; }
  }

  const char* wbase = (const char*)W1ws;

  // STAGE: 4 gload_lds per thread for K-step kt into buf bufi.
  auto STAGE = [&](int kt, int bufi) {
    char* base = &ldsb[bufi][0];
    const int k0 = kt * BKS;
    // A: 16KB fp32 = 1024 chunks; source pre-swizzled so linear LDS dest
    // yields layout byte = row*128 + (kc ^ (row&7))*16
#pragma unroll
    for (int j = 0; j < 2; ++j) {
      int chunk = (w * 2 + j) * 64 + lane;      // 16B chunk id 0..1023
      int row = chunk >> 3, cp = chunk & 7;
      int kc = cp ^ (row & 7);                  // logical k-chunk
      gload_lds16(query + (size_t)(m0 + row) * KDIM + k0 + kc * 4,
                  base + (w * 2 + j) * 1024);
    }
    // B: pre-swizzled images, linear; hi 8KB + lo 8KB, 1 call each per wave
    const char* tb = wbase + ((size_t)(nb * NKT + kt) * 2) * 8192;
    gload_lds16(tb + w * 1024 + lane * 16, base + 16384 + w * 1024);
    gload_lds16(tb + 8192 + w * 1024 + lane * 16, base + 24576 + w * 1024);
  };

  STAGE(0, 0);
  for (int kt = 0; kt < NKT; ++kt) {
    const int cur = kt & 1;
    if (kt + 1 < NKT) {
      STAGE(kt + 1, cur ^ 1);
      asm volatile("s_waitcnt vmcnt(4)" ::: "memory");  // cur's 4 landed
    } else {
      asm volatile("s_waitcnt vmcnt(0)" ::: "memory");
    }
    __builtin_amdgcn_s_barrier();            // all waves: cur tile ready

    const char* base = &ldsb[cur][0];
    // ---- A fragments (row = wr*32 + l31, k = ksub*16 + lk*8 + j) ----
    f16x8 afh[2], afl[2];
    {
      int row = wr * 32 + l31;
#pragma unroll
      for (int ksub = 0; ksub < 2; ++ksub) {
        int c0 = (ksub * 4 + lk * 2) ^ (row & 7);
        int c1 = (ksub * 4 + lk * 2 + 1) ^ (row & 7);
        f32x4 va = *reinterpret_cast<const f32x4*>(base + row * 128 + c0 * 16);
        f32x4 vb = *reinterpret_cast<const f32x4*>(base + row * 128 + c1 * 16);
        f16x8 h, l;
#pragma unroll
        for (int e = 0; e < 4; ++e) {
          _Float16 hh = (_Float16)va[e];
          h[e] = hh;
          l[e] = (_Float16)((va[e] - (float)hh) * 2048.0f);
        }
#pragma unroll
        for (int e = 0; e < 4; ++e) {
          _Float16 hh = (_Float16)vb[e];
          h[4 + e] = hh;
          l[4 + e] = (_Float16)((vb[e] - (float)hh) * 2048.0f);
        }
        afh[ksub] = h;
        afl[ksub] = l;
      }
    }
    // ---- B fragments (row = wc*64 + nf*32 + l31, chunk = ksub*2 + lk) ----
    f16x8 bfh[2][2], bfl[2][2];
#pragma unroll
    for (int nf = 0; nf < 2; ++nf) {
      int row = wc * 64 + nf * 32 + l31;
#pragma unroll
      for (int ksub = 0; ksub < 2; ++ksub) {
        int off = row * 64 + (swz_chunk(row, ksub * 2 + lk) << 4);
        bfh[nf][ksub] = *reinterpret_cast<const f16x8*>(base + 16384 + off);
        bfl[nf][ksub] = *reinterpret_cast<const f16x8*>(base + 24576 + off);
      }
    }
    // ---- 12 MFMA (32x32x16) ----
#pragma unroll
    for (int nf = 0; nf < 2; ++nf)
#pragma unroll
      for (int ksub = 0; ksub < 2; ++ksub) {
        acc[nf]  = __builtin_amdgcn_mfma_f32_32x32x16_f16(afh[ksub], bfh[nf][ksub], acc[nf], 0, 0, 0);
        acc2[nf] = __builtin_amdgcn_mfma_f32_32x32x16_f16(afh[ksub], bfl[nf][ksub], acc2[nf], 0, 0, 0);
        acc2[nf] = __builtin_amdgcn_mfma_f32_32x32x16_f16(afl[ksub], bfh[nf][ksub], acc2[nf], 0, 0, 0);
      }
    // ds_reads of cur complete before any wave overwrites it next iter
    asm volatile("s_waitcnt lgkmcnt(0)" ::: "memory");
    __builtin_amdgcn_s_barrier();
  }

  // ---- epilogue: z = acc + acc2*2^-11 + bias; tanh; dot with Vw ----
  // C/D layout 32x32: col = lane&31, row = (r&3) + 8*(r>>2) + 4*(lane>>5)
  float part[16];
#pragma unroll
  for (int r = 0; r < 16; ++r) part[r] = 0.f;
#pragma unroll
  for (int nf = 0; nf < 2; ++nf) {
    int col = n0 + wc * 64 + nf * 32 + l31;
    float bias = W1b[col];
    float vw = Vw[col];
#pragma unroll
    for (int r = 0; r < 16; ++r) {
      float z = acc[nf][r] + acc2[nf][r] * 4.8828125e-4f + bias;
      part[r] += tanhf(z) * vw;
    }
  }
  // reduce across the 32 column-lanes (stays within each 32-lane half)
#pragma unroll
  for (int off = 1; off < 32; off <<= 1)
#pragma unroll
    for (int r = 0; r < 16; ++r)
      part[r] += __shfl_xor(part[r], off, 64);
  if (l31 == 0) {
#pragma unroll
    for (int r = 0; r < 16; ++r) {
      int row_local = (r & 3) + 8 * (r >> 2) + 4 * lk;
      red[wc][wr * 32 + row_local] = part[r];
    }
  }
  __syncthreads();
  if (tid < BM)
    raw_part[(size_t)nb * TM + m0 + tid] = red[0][tid] + red[1][tid];
}

// ---------------------------------------------------------------------------
// Kernel 3: fused NMS + top-p. 8 blocks (one per batch) x 512 threads.
// Wave w = cine w of the batch. Also emits a deterministic compacted
// (idx, attn) list per batch for the context kernel.
// Writes attn (out+12288) and masked_score (out+28672).
// ---------------------------------------------------------------------------
__global__ __launch_bounds__(512) void nms_topp_kernel(
    const float* __restrict__ raw_part,
    const float* __restrict__ Vb,
    float* __restrict__ out,
    int* __restrict__ ccnt,
    int* __restrict__ cidx,
    float* __restrict__ cval)
{
  const int b = blockIdx.x;
  const int tid = threadIdx.x;
  const int lane = tid & 63;
  const int w = tid >> 6;           // wave = cine within batch
  const int cine = b * 8 + w;

  __shared__ float s[8][256];       // scores, then probs (flat = batch layout)
  __shared__ int order[8][256];     // NMS rank order; aliased as cnz after
  __shared__ float sv[2048];
  __shared__ int sidx[2048];
  __shared__ unsigned char msk[2048];
  __shared__ float red[512];
  __shared__ int wseg[32];
  __shared__ int wbase[33];
  __shared__ int nnz_s;

  // ---- per-wave: scores ----
  float pv[4];
  const float vb = Vb[0];
#pragma unroll
  for (int q = 0; q < 4; ++q) {
    int p = q * 64 + lane;
    int idx = cine * 256 + p;
    float r = vb;
#pragma unroll
    for (int sl = 0; sl < 4; ++sl) r += raw_part[sl * TM + idx];
    pv[q] = r;
    s[w][p] = r;
  }
  __syncthreads();
  // ---- stable rank (value desc, index asc) ----
#pragma unroll
  for (int q = 0; q < 4; ++q) {
    int p = q * 64 + lane;
    float st = pv[q];
    int rk = 0;
    for (int j = 0; j < 256; ++j) {
      float sj = s[w][j];
      rk += (sj > st) || (sj == st && j < p);
    }
    order[w][rk] = p;
  }
  __syncthreads();
  // ---- greedy NMS, per-wave serial over ranks ----
  unsigned m = 0xFu;
  for (int r = 0; r < 256; ++r) {
    int i = order[w][r];
    int qi = i >> 6, li = i & 63;
    unsigned long long ball = __ballot((lane == li) && ((m >> qi) & 1u));
    if (ball) {
#pragma unroll
      for (int q = 0; q < 4; ++q) {
        int d = q * 64 + lane - i;
        if (d != 0 && d <= 13 && d >= -13) m &= ~(1u << q);
      }
    } else if (lane == li) {
      s[w][i] = -3.402823466385289e+38f;  // NEG_INF
    }
  }
  __syncthreads();
  // ---- sigmoid in place; probs flat layout p[i] = s[i>>8][i&255] ----
  float* p = &s[0][0];
  int* cnz = &order[0][0];          // alias: order no longer needed
  if (tid == 0) nnz_s = 0;
#pragma unroll
  for (int q = 0; q < 4; ++q) {
    int pos = q * 64 + lane;
    s[w][pos] = 1.0f / (1.0f + expf(-s[w][pos]));
    msk[w * 256 + pos] = 0;
  }
  __syncthreads();
  // ---- total sum + nonzero compaction (order-free; ranks fix order) ----
  float lsum = 0.f;
#pragma unroll
  for (int i0 = 0; i0 < 4; ++i0) {
    int i = tid + i0 * 512;
    float v = p[i];
    lsum += v;
    if (v > 0.f) {
      int slot = atomicAdd(&nnz_s, 1);
      cnz[slot] = i;
    }
  }
  red[tid] = lsum;
  __syncthreads();
  for (int sred = 256; sred > 0; sred >>= 1) {
    if (tid < sred) red[tid] += red[tid + sred];
    __syncthreads();
  }
  const int nnz = nnz_s;
  const float total = red[0];
  // ---- stable ranks among nonzeros (value desc, index asc) ----
  for (int c = tid; c < nnz; c += 512) {
    int i = cnz[c];
    float pi = p[i];
    int rank = 0;
    for (int cc = 0; cc < nnz; ++cc) {
      int j = cnz[cc];
      float pj = p[j];
      rank += (pj > pi) || (pj == pi && j < i);
    }
    sv[rank] = pi;
    sidx[rank] = i;
  }
  __syncthreads();
  if (tid == 0) {
    float denom = total + 1e-8f;
    float cum = 0.f;
    for (int r = 0; r < nnz; ++r) {
      cum += sv[r] / denom;             // norm then cumsum, like reference
      if ((cum <= 0.7f) || (r < 3)) msk[sidx[r]] = 1;
    }
  }
  __syncthreads();
  // ---- masked scores + batch sum ----
  float ls = 0.f;
#pragma unroll
  for (int i0 = 0; i0 < 4; ++i0) {
    int i = tid + i0 * 512;
    float mm = msk[i] ? p[i] : 0.f;
    sv[i] = mm;
    ls += mm;
  }
  red[tid] = ls;
  __syncthreads();
  for (int sred = 256; sred > 0; sred >>= 1) {
    if (tid < sred) red[tid] += red[tid + sred];
    __syncthreads();
  }
  const float ssum = red[0];
  const float denom = ssum + 1e-8f;
  const bool uni = (ssum <= 0.f);
  float attnv[4];
  bool kp[4];
  int offs[4];
#pragma unroll
  for (int i0 = 0; i0 < 4; ++i0) {
    int i = tid + i0 * 512;
    float mm = sv[i];
    float av = uni ? (1.0f / 2048.0f) : (mm / denom);
    out[28672 + b * 2048 + i] = mm;                      // masked_score
    out[12288 + b * 2048 + i] = av;                      // attn
    attnv[i0] = av;
    kp[i0] = (msk[i] != 0);
    unsigned long long ball = __ballot(kp[i0]);
    offs[i0] = __popcll(ball & ((1ull << lane) - 1ull));
    if (lane == 0) wseg[i0 * 8 + w] = __popcll(ball);
  }
  __syncthreads();
  if (tid == 0) {
    int run = 0;
    for (int sg = 0; sg < 32; ++sg) { wbase[sg] = run; run += wseg[sg]; }
    wbase[32] = run;
    ccnt[b] = uni ? -1 : run;
  }
  __syncthreads();
#pragma unroll
  for (int i0 = 0; i0 < 4; ++i0) {
    if (kp[i0]) {
      int pos = wbase[i0 * 8 + w] + offs[i0];
      cidx[b * 2048 + pos] = tid + i0 * 512;
      cval[b * 2048 + pos] = attnv[i0];
    }
  }
}

// ---------------------------------------------------------------------------
// Kernel 4: sparse context from compact list. grid = 8 b x 6 dchunk = 48.
// ---------------------------------------------------------------------------
__global__ __launch_bounds__(256) void ctx_kernel(
    const int* __restrict__ ccnt,
    const int* __restrict__ cidx,
    const float* __restrict__ cval,
    const float* __restrict__ values,
    float* __restrict__ out)
{
  const int b = blockIdx.x / 6;
  const int ch = blockIdx.x % 6;
  const int tid = threadIdx.x;
  const int d = ch * 256 + tid;
  __shared__ float cv[2048];
  __shared__ int ci[2048];
  const int cnt = ccnt[b];
  if (cnt >= 0) {
    for (int t = tid; t < cnt; t += 256) {
      cv[t] = cval[b * 2048 + t];
      ci[t] = cidx[b * 2048 + t];
    }
  }
  __syncthreads();
  float acc = 0.f;
  if (cnt < 0) {
    for (int t = 0; t < 2048; ++t)
      acc += values[((size_t)b * 2048 + t) * KDIM + d];
    acc *= (1.0f / 2048.0f);
  } else {
#pragma unroll 4
    for (int t = 0; t < cnt; ++t)
      acc += cv[t] * values[((size_t)b * 2048 + ci[t]) * KDIM + d];
  }
  out[b * KDIM + d] = acc;
}

// ---------------------------------------------------------------------------
extern "C" void kernel_launch(void* const* d_in, const int* in_sizes, int n_in,
                              void* d_out, int out_size, void* d_ws, size_t ws_size,
                              hipStream_t stream) {
  const float* query  = (const float*)d_in[0];
  const float* values = (const float*)d_in[1];
  const float* W1w    = (const float*)d_in[2];
  const float* W1b    = (const float*)d_in[3];
  const float* Vw     = (const float*)d_in[4];
  const float* Vb     = (const float*)d_in[5];
  float* out = (float*)d_out;

  // ws layout (bytes): W1ws [4][48][2][8192] = 3145728 |
  //   raw_part[4*16384 f32] = 262144 | ccnt[16 int] | cidx[8*2048 int] |
  //   cval[8*2048 f32]
  unsigned short* W1ws = (unsigned short*)d_ws;
  float* raw_part = (float*)((char*)d_ws + 3145728);
  int*   ccnt = (int*)((char*)d_ws + 3145728 + 262144);
  int*   cidx = ccnt + 16;
  float* cval = (float*)(cidx + 8 * 2048);

  convert_w1_kernel<<<dim3(NKT, 4), 256, 0, stream>>>(W1w, W1ws);
  gemm_score_kernel<<<512, 512, 0, stream>>>(query, W1ws, W1b, Vw, raw_part);
  nms_topp_kernel<<<8, 512, 0, stream>>>(raw_part, Vb, out, ccnt, cidx, cval);
  ctx_kernel<<<48, 256, 0, stream>>>(ccnt, cidx, cval, values, out);
}

// Round 8
// 166.756 us; speedup vs baseline: 1.0964x; 1.0964x over previous
//
#include <hip/hip_runtime.h>
#include <math.h>
#include <stdint.h>

// Problem constants
#define TM 16384   // B*C*T rows
#define NN 512     // DOUT
#define KDIM 1536  // DIN
#define BM 128
#define BN 128
#define BKS 32
#define NKT 48     // total K-steps (full K per block: tanh needs complete z)

typedef _Float16 f16x8 __attribute__((ext_vector_type(8)));
typedef __fp16 h16x2 __attribute__((ext_vector_type(2)));   // cvt_pkrtz return type
typedef float f32x4 __attribute__((ext_vector_type(4)));

__device__ __forceinline__ unsigned short f16bits(_Float16 h) {
  union { _Float16 h; unsigned short u; } cv; cv.h = h; return cv.u;
}

// B-tile swizzle (fp16, 64B rows, 4x16B chunks): chunk' = chunk ^ ((row>>1)&3).
// Measured 0 extra conflicts in R3/R5.
__device__ __forceinline__ int swz_chunk(int row, int chunk) {
  return chunk ^ ((row >> 1) & 3);
}

__device__ __forceinline__ void gload_lds16(const void* g, void* l) {
  __builtin_amdgcn_global_load_lds(
      (const __attribute__((address_space(1))) unsigned int*)g,
      (__attribute__((address_space(3))) unsigned int*)l, 16, 0, 0);
}

// ---------------------------------------------------------------------------
// Kernel 1: W1 [K=1536][N=512] fp32 -> pre-swizzled tiled fp16 hi/lo images.
// ws layout: [nblk 4][kt 48][hl 2][8192B tile]; tile image byte:
//   row*64 + swz_chunk(row, k>>3)*16 + (k&7)*2   (row = n within block)
// (unchanged since R2 — proven)
// ---------------------------------------------------------------------------
__global__ __launch_bounds__(256) void convert_w1_kernel(
    const float* __restrict__ W1,
    unsigned short* __restrict__ W1ws)
{
  const int kt = blockIdx.x;       // 0..47
  const int nb = blockIdx.y;       // 0..3
  const int tid = threadIdx.x;
  const int k0 = kt * BKS, n0 = nb * BN;
  const size_t tbase = ((size_t)(nb * NKT + kt) * 2) * 4096;  // u16 units
#pragma unroll
  for (int i = 0; i < 16; ++i) {
    int idx = tid + i * 256;       // 0..4095
    int nn = idx & 127, kk = idx >> 7;
    float f = W1[(size_t)(k0 + kk) * NN + n0 + nn];
    _Float16 h = (_Float16)f;
    _Float16 l = (_Float16)((f - (float)h) * 2048.0f);
    int off16 = nn * 32 + (swz_chunk(nn, kk >> 3) << 3) + (kk & 7);
    W1ws[tbase + off16] = f16bits(h);
    W1ws[tbase + 4096 + off16] = f16bits(l);
  }
}

// ---------------------------------------------------------------------------
// Kernel 2: GEMM z = q @ W1 + b, fp16 split-3 via mfma_f32_16x16x32_f16,
// fused tanh*Vw epilogue. 8 waves (512 thr), M-only wave partition:
// wave w owns rows w*16..w*16+15 x ALL 128 N-cols -> A conversion unique
// per element (no redundancy), direct per-wave output write (no LDS red).
// Dbuf LDS + gload_lds + counted vmcnt(4); cvt_pkrtz packed conversion.
// ---------------------------------------------------------------------------
__global__ __launch_bounds__(512, 4) void gemm_score_kernel(
    const float* __restrict__ query,
    const unsigned short* __restrict__ W1ws,
    const float* __restrict__ W1b,
    const float* __restrict__ Vw,
    float* __restrict__ raw_part)
{
  __shared__ __align__(16) char ldsb[2][32768];

  const int tid = threadIdx.x;
  const int lane = tid & 63;
  const int w = tid >> 6;                  // 0..7 — m-group (16 rows each)
  const int lrow = lane & 15;
  const int lseg = lane >> 4;              // k-segment 0..3

  // XCD-chunked bijective swizzle (512 = 8 XCD * 64), n innermost per XCD
  const int bid = blockIdx.x;
  const int lin = (bid & 7) * 64 + (bid >> 3);
  const int mb = lin >> 2, nb = lin & 3;
  const int m0 = mb * BM, n0 = nb * BN;

  f32x4 zero = {0.f, 0.f, 0.f, 0.f};
  f32x4 acc[8], acc2[8];   // per n-frag: hh and (hl+lh)*2^11
#pragma unroll
  for (int n = 0; n < 8; ++n) { acc[n] = zero; acc2[n] = zero; }

  const char* wbase = (const char*)W1ws;

  // STAGE: 4 gload_lds per thread for K-step kt into buf bufi.
  auto STAGE = [&](int kt, int bufi) {
    char* base = &ldsb[bufi][0];
    const int k0 = kt * BKS;
    // A: 16KB fp32 = 1024 chunks; source pre-swizzled so linear LDS dest
    // yields layout byte = row*128 + (kc ^ (row&7))*16
#pragma unroll
    for (int j = 0; j < 2; ++j) {
      int chunk = (w * 2 + j) * 64 + lane;      // 16B chunk id 0..1023
      int row = chunk >> 3, cp = chunk & 7;
      int kc = cp ^ (row & 7);                  // logical k-chunk
      gload_lds16(query + (size_t)(m0 + row) * KDIM + k0 + kc * 4,
                  base + (w * 2 + j) * 1024);
    }
    // B: pre-swizzled images, linear; hi 8KB + lo 8KB, 1 call each per wave
    const char* tb = wbase + ((size_t)(nb * NKT + kt) * 2) * 8192;
    gload_lds16(tb + w * 1024 + lane * 16, base + 16384 + w * 1024);
    gload_lds16(tb + 8192 + w * 1024 + lane * 16, base + 24576 + w * 1024);
  };

  STAGE(0, 0);
  for (int kt = 0; kt < NKT; ++kt) {
    const int cur = kt & 1;
    if (kt + 1 < NKT) {
      STAGE(kt + 1, cur ^ 1);
      asm volatile("s_waitcnt vmcnt(4)" ::: "memory");  // cur's 4 landed
    } else {
      asm volatile("s_waitcnt vmcnt(0)" ::: "memory");
    }
    __builtin_amdgcn_s_barrier();            // all waves: cur tile ready

    const char* base = &ldsb[cur][0];
    // ---- A fragment (unique per wave): fp32 -> hi/lo fp16, cvt_pkrtz ----
    f16x8 afh, afl;
    {
      int row = w * 16 + lrow;
      int c0 = (lseg * 2) ^ (row & 7);
      int c1 = (lseg * 2 + 1) ^ (row & 7);
      f32x4 va = *reinterpret_cast<const f32x4*>(base + row * 128 + c0 * 16);
      f32x4 vb = *reinterpret_cast<const f32x4*>(base + row * 128 + c1 * 16);
      union H8 { f16x8 v; h16x2 p[4]; } h, l;
      h.p[0] = __builtin_amdgcn_cvt_pkrtz(va[0], va[1]);
      h.p[1] = __builtin_amdgcn_cvt_pkrtz(va[2], va[3]);
      h.p[2] = __builtin_amdgcn_cvt_pkrtz(vb[0], vb[1]);
      h.p[3] = __builtin_amdgcn_cvt_pkrtz(vb[2], vb[3]);
      float r0 = (va[0] - (float)h.p[0][0]) * 2048.0f;
      float r1 = (va[1] - (float)h.p[0][1]) * 2048.0f;
      float r2 = (va[2] - (float)h.p[1][0]) * 2048.0f;
      float r3 = (va[3] - (float)h.p[1][1]) * 2048.0f;
      float r4 = (vb[0] - (float)h.p[2][0]) * 2048.0f;
      float r5 = (vb[1] - (float)h.p[2][1]) * 2048.0f;
      float r6 = (vb[2] - (float)h.p[3][0]) * 2048.0f;
      float r7 = (vb[3] - (float)h.p[3][1]) * 2048.0f;
      l.p[0] = __builtin_amdgcn_cvt_pkrtz(r0, r1);
      l.p[1] = __builtin_amdgcn_cvt_pkrtz(r2, r3);
      l.p[2] = __builtin_amdgcn_cvt_pkrtz(r4, r5);
      l.p[3] = __builtin_amdgcn_cvt_pkrtz(r6, r7);
      afh = h.v;
      afl = l.v;
    }
    // ---- B fragments + MFMA, 8 n-frags x 3 MFMA ----
#pragma unroll
    for (int nf = 0; nf < 8; ++nf) {
      int brow = nf * 16 + lrow;
      int boff = brow * 64 + (swz_chunk(brow, lseg) << 4);
      f16x8 bh = *reinterpret_cast<const f16x8*>(base + 16384 + boff);
      f16x8 bl = *reinterpret_cast<const f16x8*>(base + 24576 + boff);
      acc[nf]  = __builtin_amdgcn_mfma_f32_16x16x32_f16(afh, bh, acc[nf], 0, 0, 0);
      acc2[nf] = __builtin_amdgcn_mfma_f32_16x16x32_f16(afh, bl, acc2[nf], 0, 0, 0);
      acc2[nf] = __builtin_amdgcn_mfma_f32_16x16x32_f16(afl, bh, acc2[nf], 0, 0, 0);
    }
    // ds_reads of cur complete before any wave overwrites it next iter
    asm volatile("s_waitcnt lgkmcnt(0)" ::: "memory");
    __builtin_amdgcn_s_barrier();
  }

  // ---- epilogue: z = acc + acc2*2^-11 + bias; tanh; dot with Vw ----
  // C/D 16x16: col = lane&15, row = (lane>>4)*4 + r
  float part[4] = {0.f, 0.f, 0.f, 0.f};
#pragma unroll
  for (int nf = 0; nf < 8; ++nf) {
    int col = n0 + nf * 16 + lrow;
    float bias = W1b[col];
    float vw = Vw[col];
#pragma unroll
    for (int r = 0; r < 4; ++r) {
      float z = acc[nf][r] + acc2[nf][r] * 4.8828125e-4f + bias;
      part[r] += tanhf(z) * vw;
    }
  }
  // reduce across the 16 column-lanes (within each 16-lane group)
#pragma unroll
  for (int off = 1; off < 16; off <<= 1)
#pragma unroll
    for (int r = 0; r < 4; ++r)
      part[r] += __shfl_xor(part[r], off, 64);
  if (lrow == 0) {
    int rowb = m0 + w * 16 + lseg * 4;
#pragma unroll
    for (int r = 0; r < 4; ++r)
      raw_part[(size_t)nb * TM + rowb + r] = part[r];
  }
}

// ---------------------------------------------------------------------------
// Kernel 3: per-cine (64 blocks x 1 wave): sum partials + Vb, stable rank,
// greedy temporal NMS (radius 13) with ballot keep-test, sigmoid -> probs
// (exact R4 version — proven fastest tail)
// ---------------------------------------------------------------------------
__global__ __launch_bounds__(64) void nms_kernel(
    const float* __restrict__ raw_part,
    const float* __restrict__ Vb,
    float* __restrict__ probs)
{
  const int cine = blockIdx.x;
  const int lane = threadIdx.x;
  __shared__ float s[256];
  __shared__ int order[256];
  float sv[4];
  const float vb = Vb[0];
#pragma unroll
  for (int q = 0; q < 4; ++q) {
    int p = q * 64 + lane;
    int idx = cine * 256 + p;
    float r = vb;
#pragma unroll
    for (int sl = 0; sl < 4; ++sl) r += raw_part[sl * TM + idx];
    sv[q] = r;
    s[p] = r;
  }
  __syncthreads();
#pragma unroll
  for (int q = 0; q < 4; ++q) {
    int p = q * 64 + lane;
    float st = sv[q];
    int rk = 0;
    for (int j = 0; j < 256; ++j) {
      float sj = s[j];
      rk += (sj > st) || (sj == st && j < p);
    }
    order[rk] = p;
  }
  __syncthreads();
  unsigned m = 0xFu;
  for (int r = 0; r < 256; ++r) {
    int i = order[r];
    int qi = i >> 6, li = i & 63;
    unsigned long long ball = __ballot((lane == li) && ((m >> qi) & 1u));
    if (ball) {
#pragma unroll
      for (int q = 0; q < 4; ++q) {
        int d = q * 64 + lane - i;
        if (d != 0 && d <= 13 && d >= -13) m &= ~(1u << q);
      }
    } else if (lane == li) {
      s[i] = -3.402823466385289e+38f;  // NEG_INF
    }
  }
  __syncthreads();
#pragma unroll
  for (int q = 0; q < 4; ++q) {
    int p = q * 64 + lane;
    probs[cine * 256 + p] = 1.0f / (1.0f + expf(-s[p]));
  }
}

// ---------------------------------------------------------------------------
// Kernel 4: per-batch (8 blocks) nucleus top-p(0.7) on 2048 probs.
// Writes attn (out+12288) and masked_score (out+28672). (exact R4 version)
// ---------------------------------------------------------------------------
__global__ __launch_bounds__(256) void topp_kernel(
    const float* __restrict__ probs,
    float* __restrict__ out)
{
  const int b = blockIdx.x;
  const int tid = threadIdx.x;
  __shared__ float p[2048];
  __shared__ int cnz[2048];
  __shared__ float sv[2048];
  __shared__ int sidx[2048];
  __shared__ unsigned char msk[2048];
  __shared__ float red[256];
  __shared__ int nnz_s;

  if (tid == 0) nnz_s = 0;
  for (int i = tid; i < 2048; i += 256) {
    p[i] = probs[b * 2048 + i];
    msk[i] = 0;
  }
  __syncthreads();
  float lsum = 0.f;
  for (int i = tid; i < 2048; i += 256) {
    float v = p[i];
    lsum += v;
    if (v > 0.f) {
      int slot = atomicAdd(&nnz_s, 1);
      cnz[slot] = i;
    }
  }
  red[tid] = lsum;
  __syncthreads();
  for (int sred = 128; sred > 0; sred >>= 1) {
    if (tid < sred) red[tid] += red[tid + sred];
    __syncthreads();
  }
  const int nnz = nnz_s;
  const float total = red[0];
  for (int c = tid; c < nnz; c += 256) {
    int i = cnz[c];
    float pi = p[i];
    int rank = 0;
    for (int cc = 0; cc < nnz; ++cc) {
      int j = cnz[cc];
      float pj = p[j];
      rank += (pj > pi) || (pj == pi && j < i);
    }
    sv[rank] = pi;
    sidx[rank] = i;
  }
  __syncthreads();
  if (tid == 0) {
    float denom = total + 1e-8f;
    float cum = 0.f;
    for (int r = 0; r < nnz; ++r) {
      cum += sv[r] / denom;             // norm then cumsum, like reference
      if ((cum <= 0.7f) || (r < 3)) msk[sidx[r]] = 1;
    }
  }
  __syncthreads();
  float ls = 0.f;
  for (int i = tid; i < 2048; i += 256) {
    float m = msk[i] ? p[i] : 0.f;
    sv[i] = m;
    ls += m;
  }
  red[tid] = ls;
  __syncthreads();
  for (int sred = 128; sred > 0; sred >>= 1) {
    if (tid < sred) red[tid] += red[tid + sred];
    __syncthreads();
  }
  const float ssum = red[0];
  const float denom = ssum + 1e-8f;
  const bool uni = (ssum <= 0.f);
  for (int i = tid; i < 2048; i += 256) {
    float m = sv[i];
    out[28672 + b * 2048 + i] = m;                       // masked_score
    out[12288 + b * 2048 + i] = uni ? (1.0f / 2048.0f) : (m / denom);  // attn
  }
}

// ---------------------------------------------------------------------------
// Kernel 5: sparse context partials. grid = 8 b x 8 tgroup x 6 dchunk = 384.
// Ballot-compacted kept indices (deterministic order), ~19 rows per block.
// (exact R4 version)
// ---------------------------------------------------------------------------
__global__ __launch_bounds__(256) void ctx_part_kernel(
    const float* __restrict__ attn,     // out + 12288
    const float* __restrict__ values,
    float* __restrict__ ctxp)
{
  const int ch = blockIdx.x % 6;
  const int g  = (blockIdx.x / 6) & 7;
  const int b  = blockIdx.x / 48;
  const int tid = threadIdx.x;
  const int lane = tid & 63, w = tid >> 6;
  __shared__ float av[256];
  __shared__ int   idx[256];
  __shared__ int   wcnt[4];

  float a = attn[b * 2048 + g * 256 + tid];
  unsigned long long mask = __ballot(a != 0.f);
  if (lane == 0) wcnt[w] = __popcll(mask);
  __syncthreads();
  int base = 0;
  for (int i = 0; i < w; ++i) base += wcnt[i];
  if (a != 0.f) {
    int pos = base + __popcll(mask & ((1ull << lane) - 1ull));
    av[pos] = a;
    idx[pos] = g * 256 + tid;
  }
  __syncthreads();
  const int total = wcnt[0] + wcnt[1] + wcnt[2] + wcnt[3];
  const int d = ch * 256 + tid;
  float acc = 0.f;
#pragma unroll 4
  for (int t = 0; t < total; ++t)
    acc += av[t] * values[((size_t)b * 2048 + idx[t]) * KDIM + d];
  ctxp[((size_t)(b * 8 + g)) * KDIM + d] = acc;
}

__global__ __launch_bounds__(256) void ctx_reduce_kernel(
    const float* __restrict__ ctxp,
    float* __restrict__ out)
{
  const int i = blockIdx.x * 256 + threadIdx.x;  // 0..12287
  const int b = i / KDIM, d = i % KDIM;
  float sum = 0.f;
#pragma unroll
  for (int g = 0; g < 8; ++g) sum += ctxp[((size_t)(b * 8 + g)) * KDIM + d];
  out[i] = sum;
}

// ---------------------------------------------------------------------------
extern "C" void kernel_launch(void* const* d_in, const int* in_sizes, int n_in,
                              void* d_out, int out_size, void* d_ws, size_t ws_size,
                              hipStream_t stream) {
  const float* query  = (const float*)d_in[0];
  const float* values = (const float*)d_in[1];
  const float* W1w    = (const float*)d_in[2];
  const float* W1b    = (const float*)d_in[3];
  const float* Vw     = (const float*)d_in[4];
  const float* Vb     = (const float*)d_in[5];
  float* out = (float*)d_out;

  // ws layout (bytes): W1ws [4][48][2][8192] = 3145728 |
  //   raw_part[4*16384 f32] | probs[16384 f32] | ctxp[64*1536 f32]
  unsigned short* W1ws = (unsigned short*)d_ws;
  float* raw_part = (float*)((char*)d_ws + 3145728);
  float* probs    = raw_part + 4 * TM;
  float* ctxp     = probs + TM;

  convert_w1_kernel<<<dim3(NKT, 4), 256, 0, stream>>>(W1w, W1ws);
  gemm_score_kernel<<<512, 512, 0, stream>>>(query, W1ws, W1b, Vw, raw_part);
  nms_kernel<<<64, 64, 0, stream>>>(raw_part, Vb, probs);
  topp_kernel<<<8, 256, 0, stream>>>(probs, out);
  ctx_part_kernel<<<384, 256, 0, stream>>>(out + 12288, values, ctxp);
  ctx_reduce_kernel<<<48, 256, 0, stream>>>(ctxp, out);
}

// Round 9
// 164.873 us; speedup vs baseline: 1.1089x; 1.0114x over previous
//
#include <hip/hip_runtime.h>
#include <math.h>
#include <stdint.h>

// Problem constants
#define TM 16384   // B*C*T rows
#define NN 512     // DOUT
#define KDIM 1536  // DIN
#define BM 128
#define BN 128
#define BKS 32
#define NKT 48     // total K-steps (full K per block: tanh needs complete z)

typedef _Float16 f16x8 __attribute__((ext_vector_type(8)));
typedef __fp16 h16x2 __attribute__((ext_vector_type(2)));   // cvt_pkrtz return type
typedef float f32x4 __attribute__((ext_vector_type(4)));

__device__ __forceinline__ unsigned short f16bits(_Float16 h) {
  union { _Float16 h; unsigned short u; } cv; cv.h = h; return cv.u;
}

// B-tile swizzle (fp16, 64B rows, 4x16B chunks): chunk' = chunk ^ ((row>>1)&3).
__device__ __forceinline__ int swz_chunk(int row, int chunk) {
  return chunk ^ ((row >> 1) & 3);
}

__device__ __forceinline__ void gload_lds16(const void* g, void* l) {
  __builtin_amdgcn_global_load_lds(
      (const __attribute__((address_space(1))) unsigned int*)g,
      (__attribute__((address_space(3))) unsigned int*)l, 16, 0, 0);
}

// ---------------------------------------------------------------------------
// Kernel 1: W1 [K=1536][N=512] fp32 -> pre-swizzled tiled fp16 hi/lo images.
// ws layout: [nblk 4][kt 48][hl 2][8192B tile]; tile image byte:
//   row*64 + swz_chunk(row, k>>3)*16 + (k&7)*2   (row = n within block)
// (unchanged since R2 — proven)
// ---------------------------------------------------------------------------
__global__ __launch_bounds__(256) void convert_w1_kernel(
    const float* __restrict__ W1,
    unsigned short* __restrict__ W1ws)
{
  const int kt = blockIdx.x;       // 0..47
  const int nb = blockIdx.y;       // 0..3
  const int tid = threadIdx.x;
  const int k0 = kt * BKS, n0 = nb * BN;
  const size_t tbase = ((size_t)(nb * NKT + kt) * 2) * 4096;  // u16 units
#pragma unroll
  for (int i = 0; i < 16; ++i) {
    int idx = tid + i * 256;       // 0..4095
    int nn = idx & 127, kk = idx >> 7;
    float f = W1[(size_t)(k0 + kk) * NN + n0 + nn];
    _Float16 h = (_Float16)f;
    _Float16 l = (_Float16)((f - (float)h) * 2048.0f);
    int off16 = nn * 32 + (swz_chunk(nn, kk >> 3) << 3) + (kk & 7);
    W1ws[tbase + off16] = f16bits(h);
    W1ws[tbase + 4096 + off16] = f16bits(l);
  }
}

// ---------------------------------------------------------------------------
// Kernel 2: GEMM z = q @ W1 + b, fp16 split-3 via mfma_f32_16x16x32_f16,
// fused tanh*Vw epilogue. 8 waves, M-only wave partition (wave = 16 rows x
// all 128 cols). R9: all staging addresses strength-reduced to pointer
// increments; LDS frag offsets hoisted out of the K-loop; setprio around
// the MFMA cluster. Dbuf LDS + gload_lds + counted vmcnt(4).
// ---------------------------------------------------------------------------
__global__ __launch_bounds__(512, 4) void gemm_score_kernel(
    const float* __restrict__ query,
    const unsigned short* __restrict__ W1ws,
    const float* __restrict__ W1b,
    const float* __restrict__ Vw,
    float* __restrict__ raw_part)
{
  __shared__ __align__(16) char ldsb[2][32768];

  const int tid = threadIdx.x;
  const int lane = tid & 63;
  const int w = tid >> 6;                  // 0..7 — m-group (16 rows each)
  const int lrow = lane & 15;
  const int lseg = lane >> 4;              // k-segment 0..3

  // XCD-chunked bijective swizzle (512 = 8 XCD * 64), n innermost per XCD
  const int bid = blockIdx.x;
  const int lin = (bid & 7) * 64 + (bid >> 3);
  const int mb = lin >> 2, nb = lin & 3;
  const int m0 = mb * BM, n0 = nb * BN;

  f32x4 zero = {0.f, 0.f, 0.f, 0.f};
  f32x4 acc[8], acc2[8];   // per n-frag: hh and (hl+lh)*2^11
#pragma unroll
  for (int n = 0; n < 8; ++n) { acc[n] = zero; acc2[n] = zero; }

  char* const ldsbase = &ldsb[0][0];

  // ---- persistent staging pointers (advance per K-step) ----
  const char* aG0;
  const char* aG1;
  {
    int chunk0 = (w * 2 + 0) * 64 + lane;          // 16B chunk id
    int row0 = chunk0 >> 3, cp0 = chunk0 & 7;
    int kc0 = cp0 ^ (row0 & 7);
    aG0 = (const char*)(query + (size_t)(m0 + row0) * KDIM + kc0 * 4);
    int chunk1 = (w * 2 + 1) * 64 + lane;
    int row1 = chunk1 >> 3, cp1 = chunk1 & 7;
    int kc1 = cp1 ^ (row1 & 7);
    aG1 = (const char*)(query + (size_t)(m0 + row1) * KDIM + kc1 * 4);
  }
  const char* bGH = (const char*)W1ws + (size_t)(nb * NKT) * 16384
                    + w * 1024 + lane * 16;
  const char* bGL = bGH + 8192;

  // ---- loop-invariant LDS offsets (held in registers) ----
  const int ldsA0 = (w * 2 + 0) * 1024;            // staging dests
  const int ldsA1 = (w * 2 + 1) * 1024;
  const int ldsBH = 16384 + w * 1024;
  const int ldsBL = 24576 + w * 1024;
  const int rowA = w * 16 + lrow;                  // A frag read offsets
  const int offA0 = rowA * 128 + (((lseg * 2) ^ (rowA & 7)) << 4);
  const int offA1 = rowA * 128 + (((lseg * 2 + 1) ^ (rowA & 7)) << 4);
  int boffH[8], boffL[8];                          // B frag read offsets
#pragma unroll
  for (int nf = 0; nf < 8; ++nf) {
    int brow = nf * 16 + lrow;
    boffH[nf] = 16384 + brow * 64 + (swz_chunk(brow, lseg) << 4);
    boffL[nf] = boffH[nf] + 8192;
  }

  // STAGE into buf bufi, then advance global pointers.
  auto STAGE = [&](int bufi) {
    char* base = ldsbase + (bufi << 15);
    gload_lds16(aG0, base + ldsA0);
    gload_lds16(aG1, base + ldsA1);
    gload_lds16(bGH, base + ldsBH);
    gload_lds16(bGL, base + ldsBL);
    aG0 += BKS * 4;          // 128 B
    aG1 += BKS * 4;
    bGH += 16384;
    bGL += 16384;
  };

  STAGE(0);
  for (int kt = 0; kt < NKT; ++kt) {
    const int cur = kt & 1;
    if (kt + 1 < NKT) {
      STAGE(cur ^ 1);
      asm volatile("s_waitcnt vmcnt(4)" ::: "memory");  // cur's 4 landed
    } else {
      asm volatile("s_waitcnt vmcnt(0)" ::: "memory");
    }
    __builtin_amdgcn_s_barrier();            // all waves: cur tile ready

    const char* base = ldsbase + (cur << 15);
    // ---- A fragment: fp32 -> hi/lo fp16, cvt_pkrtz ----
    f16x8 afh, afl;
    {
      f32x4 va = *reinterpret_cast<const f32x4*>(base + offA0);
      f32x4 vb = *reinterpret_cast<const f32x4*>(base + offA1);
      union H8 { f16x8 v; h16x2 p[4]; } h, l;
      h.p[0] = __builtin_amdgcn_cvt_pkrtz(va[0], va[1]);
      h.p[1] = __builtin_amdgcn_cvt_pkrtz(va[2], va[3]);
      h.p[2] = __builtin_amdgcn_cvt_pkrtz(vb[0], vb[1]);
      h.p[3] = __builtin_amdgcn_cvt_pkrtz(vb[2], vb[3]);
      float r0 = (va[0] - (float)h.p[0][0]) * 2048.0f;
      float r1 = (va[1] - (float)h.p[0][1]) * 2048.0f;
      float r2 = (va[2] - (float)h.p[1][0]) * 2048.0f;
      float r3 = (va[3] - (float)h.p[1][1]) * 2048.0f;
      float r4 = (vb[0] - (float)h.p[2][0]) * 2048.0f;
      float r5 = (vb[1] - (float)h.p[2][1]) * 2048.0f;
      float r6 = (vb[2] - (float)h.p[3][0]) * 2048.0f;
      float r7 = (vb[3] - (float)h.p[3][1]) * 2048.0f;
      l.p[0] = __builtin_amdgcn_cvt_pkrtz(r0, r1);
      l.p[1] = __builtin_amdgcn_cvt_pkrtz(r2, r3);
      l.p[2] = __builtin_amdgcn_cvt_pkrtz(r4, r5);
      l.p[3] = __builtin_amdgcn_cvt_pkrtz(r6, r7);
      afh = h.v;
      afl = l.v;
    }
    // ---- B fragments + MFMA, 8 n-frags x 3 MFMA ----
    __builtin_amdgcn_s_setprio(1);
#pragma unroll
    for (int nf = 0; nf < 8; ++nf) {
      f16x8 bh = *reinterpret_cast<const f16x8*>(base + boffH[nf]);
      f16x8 bl = *reinterpret_cast<const f16x8*>(base + boffL[nf]);
      acc[nf]  = __builtin_amdgcn_mfma_f32_16x16x32_f16(afh, bh, acc[nf], 0, 0, 0);
      acc2[nf] = __builtin_amdgcn_mfma_f32_16x16x32_f16(afh, bl, acc2[nf], 0, 0, 0);
      acc2[nf] = __builtin_amdgcn_mfma_f32_16x16x32_f16(afl, bh, acc2[nf], 0, 0, 0);
    }
    __builtin_amdgcn_s_setprio(0);
    // ds_reads of cur complete before any wave overwrites it next iter
    asm volatile("s_waitcnt lgkmcnt(0)" ::: "memory");
    __builtin_amdgcn_s_barrier();
  }

  // ---- epilogue: z = acc + acc2*2^-11 + bias; tanh; dot with Vw ----
  // C/D 16x16: col = lane&15, row = (lane>>4)*4 + r
  float part[4] = {0.f, 0.f, 0.f, 0.f};
#pragma unroll
  for (int nf = 0; nf < 8; ++nf) {
    int col = n0 + nf * 16 + lrow;
    float bias = W1b[col];
    float vw = Vw[col];
#pragma unroll
    for (int r = 0; r < 4; ++r) {
      float z = acc[nf][r] + acc2[nf][r] * 4.8828125e-4f + bias;
      part[r] += tanhf(z) * vw;
    }
  }
  // reduce across the 16 column-lanes (within each 16-lane group)
#pragma unroll
  for (int off = 1; off < 16; off <<= 1)
#pragma unroll
    for (int r = 0; r < 4; ++r)
      part[r] += __shfl_xor(part[r], off, 64);
  if (lrow == 0) {
    int rowb = m0 + w * 16 + lseg * 4;
#pragma unroll
    for (int r = 0; r < 4; ++r)
      raw_part[(size_t)nb * TM + rowb + r] = part[r];
  }
}

// ---------------------------------------------------------------------------
// Kernel 3: per-cine (64 blocks x 1 wave): sum partials + Vb, stable rank,
// greedy temporal NMS (radius 13) with ballot keep-test, sigmoid -> probs
// (exact R4 version — proven fastest tail)
// ---------------------------------------------------------------------------
__global__ __launch_bounds__(64) void nms_kernel(
    const float* __restrict__ raw_part,
    const float* __restrict__ Vb,
    float* __restrict__ probs)
{
  const int cine = blockIdx.x;
  const int lane = threadIdx.x;
  __shared__ float s[256];
  __shared__ int order[256];
  float sv[4];
  const float vb = Vb[0];
#pragma unroll
  for (int q = 0; q < 4; ++q) {
    int p = q * 64 + lane;
    int idx = cine * 256 + p;
    float r = vb;
#pragma unroll
    for (int sl = 0; sl < 4; ++sl) r += raw_part[sl * TM + idx];
    sv[q] = r;
    s[p] = r;
  }
  __syncthreads();
#pragma unroll
  for (int q = 0; q < 4; ++q) {
    int p = q * 64 + lane;
    float st = sv[q];
    int rk = 0;
    for (int j = 0; j < 256; ++j) {
      float sj = s[j];
      rk += (sj > st) || (sj == st && j < p);
    }
    order[rk] = p;
  }
  __syncthreads();
  unsigned m = 0xFu;
  for (int r = 0; r < 256; ++r) {
    int i = order[r];
    int qi = i >> 6, li = i & 63;
    unsigned long long ball = __ballot((lane == li) && ((m >> qi) & 1u));
    if (ball) {
#pragma unroll
      for (int q = 0; q < 4; ++q) {
        int d = q * 64 + lane - i;
        if (d != 0 && d <= 13 && d >= -13) m &= ~(1u << q);
      }
    } else if (lane == li) {
      s[i] = -3.402823466385289e+38f;  // NEG_INF
    }
  }
  __syncthreads();
#pragma unroll
  for (int q = 0; q < 4; ++q) {
    int p = q * 64 + lane;
    probs[cine * 256 + p] = 1.0f / (1.0f + expf(-s[p]));
  }
}

// ---------------------------------------------------------------------------
// Kernel 4: per-batch (8 blocks) nucleus top-p(0.7) on 2048 probs.
// Writes attn (out+12288) and masked_score (out+28672). (exact R4 version)
// ---------------------------------------------------------------------------
__global__ __launch_bounds__(256) void topp_kernel(
    const float* __restrict__ probs,
    float* __restrict__ out)
{
  const int b = blockIdx.x;
  const int tid = threadIdx.x;
  __shared__ float p[2048];
  __shared__ int cnz[2048];
  __shared__ float sv[2048];
  __shared__ int sidx[2048];
  __shared__ unsigned char msk[2048];
  __shared__ float red[256];
  __shared__ int nnz_s;

  if (tid == 0) nnz_s = 0;
  for (int i = tid; i < 2048; i += 256) {
    p[i] = probs[b * 2048 + i];
    msk[i] = 0;
  }
  __syncthreads();
  float lsum = 0.f;
  for (int i = tid; i < 2048; i += 256) {
    float v = p[i];
    lsum += v;
    if (v > 0.f) {
      int slot = atomicAdd(&nnz_s, 1);
      cnz[slot] = i;
    }
  }
  red[tid] = lsum;
  __syncthreads();
  for (int sred = 128; sred > 0; sred >>= 1) {
    if (tid < sred) red[tid] += red[tid + sred];
    __syncthreads();
  }
  const int nnz = nnz_s;
  const float total = red[0];
  for (int c = tid; c < nnz; c += 256) {
    int i = cnz[c];
    float pi = p[i];
    int rank = 0;
    for (int cc = 0; cc < nnz; ++cc) {
      int j = cnz[cc];
      float pj = p[j];
      rank += (pj > pi) || (pj == pi && j < i);
    }
    sv[rank] = pi;
    sidx[rank] = i;
  }
  __syncthreads();
  if (tid == 0) {
    float denom = total + 1e-8f;
    float cum = 0.f;
    for (int r = 0; r < nnz; ++r) {
      cum += sv[r] / denom;             // norm then cumsum, like reference
      if ((cum <= 0.7f) || (r < 3)) msk[sidx[r]] = 1;
    }
  }
  __syncthreads();
  float ls = 0.f;
  for (int i = tid; i < 2048; i += 256) {
    float m = msk[i] ? p[i] : 0.f;
    sv[i] = m;
    ls += m;
  }
  red[tid] = ls;
  __syncthreads();
  for (int sred = 128; sred > 0; sred >>= 1) {
    if (tid < sred) red[tid] += red[tid + sred];
    __syncthreads();
  }
  const float ssum = red[0];
  const float denom = ssum + 1e-8f;
  const bool uni = (ssum <= 0.f);
  for (int i = tid; i < 2048; i += 256) {
    float m = sv[i];
    out[28672 + b * 2048 + i] = m;                       // masked_score
    out[12288 + b * 2048 + i] = uni ? (1.0f / 2048.0f) : (m / denom);  // attn
  }
}

// ---------------------------------------------------------------------------
// Kernel 5: sparse context partials. grid = 8 b x 8 tgroup x 6 dchunk = 384.
// Ballot-compacted kept indices (deterministic order), ~19 rows per block.
// (exact R4 version)
// ---------------------------------------------------------------------------
__global__ __launch_bounds__(256) void ctx_part_kernel(
    const float* __restrict__ attn,     // out + 12288
    const float* __restrict__ values,
    float* __restrict__ ctxp)
{
  const int ch = blockIdx.x % 6;
  const int g  = (blockIdx.x / 6) & 7;
  const int b  = blockIdx.x / 48;
  const int tid = threadIdx.x;
  const int lane = tid & 63, w = tid >> 6;
  __shared__ float av[256];
  __shared__ int   idx[256];
  __shared__ int   wcnt[4];

  float a = attn[b * 2048 + g * 256 + tid];
  unsigned long long mask = __ballot(a != 0.f);
  if (lane == 0) wcnt[w] = __popcll(mask);
  __syncthreads();
  int base = 0;
  for (int i = 0; i < w; ++i) base += wcnt[i];
  if (a != 0.f) {
    int pos = base + __popcll(mask & ((1ull << lane) - 1ull));
    av[pos] = a;
    idx[pos] = g * 256 + tid;
  }
  __syncthreads();
  const int total = wcnt[0] + wcnt[1] + wcnt[2] + wcnt[3];
  const int d = ch * 256 + tid;
  float acc = 0.f;
#pragma unroll 4
  for (int t = 0; t < total; ++t)
    acc += av[t] * values[((size_t)b * 2048 + idx[t]) * KDIM + d];
  ctxp[((size_t)(b * 8 + g)) * KDIM + d] = acc;
}

__global__ __launch_bounds__(256) void ctx_reduce_kernel(
    const float* __restrict__ ctxp,
    float* __restrict__ out)
{
  const int i = blockIdx.x * 256 + threadIdx.x;  // 0..12287
  const int b = i / KDIM, d = i % KDIM;
  float sum = 0.f;
#pragma unroll
  for (int g = 0; g < 8; ++g) sum += ctxp[((size_t)(b * 8 + g)) * KDIM + d];
  out[i] = sum;
}

// ---------------------------------------------------------------------------
extern "C" void kernel_launch(void* const* d_in, const int* in_sizes, int n_in,
                              void* d_out, int out_size, void* d_ws, size_t ws_size,
                              hipStream_t stream) {
  const float* query  = (const float*)d_in[0];
  const float* values = (const float*)d_in[1];
  const float* W1w    = (const float*)d_in[2];
  const float* W1b    = (const float*)d_in[3];
  const float* Vw     = (const float*)d_in[4];
  const float* Vb     = (const float*)d_in[5];
  float* out = (float*)d_out;

  // ws layout (bytes): W1ws [4][48][2][8192] = 3145728 |
  //   raw_part[4*16384 f32] | probs[16384 f32] | ctxp[64*1536 f32]
  unsigned short* W1ws = (unsigned short*)d_ws;
  float* raw_part = (float*)((char*)d_ws + 3145728);
  float* probs    = raw_part + 4 * TM;
  float* ctxp     = probs + TM;

  convert_w1_kernel<<<dim3(NKT, 4), 256, 0, stream>>>(W1w, W1ws);
  gemm_score_kernel<<<512, 512, 0, stream>>>(query, W1ws, W1b, Vw, raw_part);
  nms_kernel<<<64, 64, 0, stream>>>(raw_part, Vb, probs);
  topp_kernel<<<8, 256, 0, stream>>>(probs, out);
  ctx_part_kernel<<<384, 256, 0, stream>>>(out + 12288, values, ctxp);
  ctx_reduce_kernel<<<48, 256, 0, stream>>>(ctxp, out);
}